// Round 1
// baseline (878.349 us; speedup 1.0000x reference)
//
#include <hip/hip_runtime.h>
#include <math.h>

// ArcFace loss, N=2048 rows, C=85742 cols, fp32 in, scalar fp32 out.
//
// Per row: loss_i = logsumexp_j(logits) - logits[target]
// where logits = 32*cos everywhere except the target column, which gets the
// margin value 32*phi.  Only ONE column differs, so we stream the plain
// 32*cos logsumexp and patch the target column afterwards:
//   s     = sum_j 2^(K*(c_j - 1))          (K = 32*log2(e); factor 2^K out)
//   s_mod = s - 2^(K*(c_t-1)) + 2^(K*(phi_t-1))
//   loss  = ln2*log2(s_mod) + 32 - 32*phi_t
// Exponents lie in [-92.3, 0]: no overflow, and row max ~= 1 so s >= ~1
// (no destructive underflow).  No online max needed -> branchless hot loop.
//
// V2: float4 (dwordx4, 16B/lane) streaming loads + 4-deep hand unroll with
// 4 independent accumulators.  Row pitch 342968 B == 8 (mod 16), so odd
// rows peel a 2-float prefix (even rows a 2-float tail) to keep the float4
// pointer 16B-aligned: 21435 aligned float4 per row exactly.

#define NROWS 2048
#define NCOLS 85742
#define NV4   21435   // float4 loads per row after the 8B alignment peel

#define COS_M 0.8775825618903728f
#define SIN_M 0.479425538604203f
#define TH   (-0.8775825618903728f)   // cos(pi - 0.5)
#define MM    0.2397127693021015f     // sin(pi - 0.5) * 0.5
#define KLOG2 46.16624130844683f      // 32 * log2(e)
#define LN2   0.6931471805599453f

__device__ __forceinline__ float exp2_fast(float x) {
#if __has_builtin(__builtin_amdgcn_exp2f)
    return __builtin_amdgcn_exp2f(x);   // single v_exp_f32
#else
    return exp2f(x);
#endif
}

__device__ __forceinline__ float term(float c) {
    c = fminf(1.0f, fmaxf(-1.0f, c));            // v_med3 clamp
    return exp2_fast(fmaf(KLOG2, c, -KLOG2));
}

__device__ __forceinline__ float term4(float4 v) {
    return (term(v.x) + term(v.y)) + (term(v.z) + term(v.w));
}

__global__ __launch_bounds__(256) void arcface_loss_kernel(
    const float* __restrict__ cosine,
    const int*   __restrict__ targets,
    float*       __restrict__ out)
{
    const int row = blockIdx.x;
    const int tid = threadIdx.x;
    const size_t base = (size_t)row * NCOLS;

    // Row byte offset = row*342968 == 8 (mod 16) for odd rows: peel 2 floats
    // in front (odd rows) or at the back (even rows) so float4 is aligned.
    const int pre = (row & 1) << 1;   // 0 or 2 elements
    const float4* __restrict__ vp = (const float4*)(cosine + base + pre);

    // Main loop: 4 dwordx4 loads in flight per wave (64 B/lane), 4
    // independent accumulators (no serial add chain on the load path).
    float s0 = 0.0f, s1 = 0.0f, s2 = 0.0f, s3 = 0.0f;
    int j = tid;
    for (; j + 768 < NV4; j += 1024) {
        float4 a = vp[j];
        float4 b = vp[j + 256];
        float4 c = vp[j + 512];
        float4 d = vp[j + 768];
        s0 += term4(a);
        s1 += term4(b);
        s2 += term4(c);
        s3 += term4(d);
    }
    for (; j < NV4; j += 256)
        s0 += term4(vp[j]);

    float s = (s0 + s1) + (s2 + s3);

    // The 2 peeled scalars (prefix of odd rows / tail of even rows).
    if (tid < 2) {
        const size_t off = pre ? (size_t)tid : (size_t)(NCOLS - 2 + tid);
        s += term(cosine[base + off]);
    }

    // Wave-64 shuffle reduction.
#pragma unroll
    for (int off = 32; off > 0; off >>= 1)
        s += __shfl_down(s, off, 64);

    __shared__ float ws[4];
    const int wave = tid >> 6;
    const int lane = tid & 63;
    if (lane == 0) ws[wave] = s;
    __syncthreads();

    if (tid == 0) {
        float st = ws[0] + ws[1] + ws[2] + ws[3];

        const int t = targets[row];
        float ct = fminf(1.0f, fmaxf(-1.0f, cosine[base + (size_t)t]));
        float sn = sqrtf(fminf(1.0f, fmaxf(0.0f, 1.0f - ct * ct)));
        float phi = ct * COS_M - sn * SIN_M;          // cos(theta + m)
        phi = (ct > TH) ? phi : (ct - MM);            // fallback branch

        // Patch the target column (same exp2(fma) form as the hot loop).
        float smod = st - exp2_fast(fmaf(KLOG2, ct,  -KLOG2))
                        + exp2_fast(fmaf(KLOG2, phi, -KLOG2));

        float loss = LN2 * log2f(smod) + 32.0f - 32.0f * phi;
        atomicAdd(out, loss * (1.0f / (float)NROWS));
    }
}

extern "C" void kernel_launch(void* const* d_in, const int* in_sizes, int n_in,
                              void* d_out, int out_size, void* d_ws, size_t ws_size,
                              hipStream_t stream) {
    const float* cosine  = (const float*)d_in[0];
    const int*   targets = (const int*)d_in[1];
    float*       out     = (float*)d_out;

    // d_out is re-poisoned to 0xAA before every timed launch; zero it on-stream
    // (async memset is graph-capture legal).
    hipMemsetAsync(out, 0, sizeof(float), stream);

    arcface_loss_kernel<<<NROWS, 256, 0, stream>>>(cosine, targets, out);
}